// Round 6
// baseline (298.152 us; speedup 1.0000x reference)
//
#include <hip/hip_runtime.h>
#include <hip/hip_bf16.h>

// Problem constants (fixed by the reference harness)
#define NN 65536            // total nodes
#define NE (NN * 16)        // total edges = 1,048,576
#define NG 32               // graphs
#define MAXD 64             // ELL slots per node (max in-degree ~45 for Poisson(16))

// Workspace layout (bytes)
#define WS_CURSOR 0                         // NN ints        = 262144
#define WS_SUMMED 262144                    // NG*30 floats   = 3840
#define WS_ELL    1048576                   // NN*MAXD ints   = 16 MB
#define WS_ZA     (WS_ELL + NN * MAXD * 4)  // NN*32 f32      = 8 MB
#define WS_ZB     (WS_ZA + NN * 32 * 4)
#define WS_H1     (WS_ZB + NN * 32 * 4)
#define WS_H2     (WS_H1 + NN * 32 * 4)
#define WS_H3     (WS_H2 + NN * 32 * 4)
#define WS_Z4     (WS_H3 + NN * 32 * 4)     // NN f32

// XCD-affine swizzle: 8 XCDs, round-robin dispatch assumed (blockIdx % 8).
// Gives XCD x a contiguous original-block range -> 4 graphs per XCD.
__device__ __forceinline__ int xcd_swz(int b, int chunk) {
    return (b & 7) * chunk + (b >> 3);
}

// ---------------------------------------------------------------------------
// Fused: ELL build (4 edges/thread, atomics issued FIRST so their latency
// hides under the gemm tile) + z1 = feat (N x 128) @ W0 (128 x 32).
// 1024 blocks: block handles 64 gemm rows AND 1024 edges.
__global__ __launch_bounds__(256) void k_gb(const float* __restrict__ feat,
                                            const float* __restrict__ W0,
                                            float* __restrict__ z1,
                                            const int* __restrict__ ei,
                                            int* __restrict__ cursor,
                                            int* __restrict__ ell) {
    __shared__ float wl[32 * 132];   // W transposed: wl[c][k], stride 132
    __shared__ float hl[64 * 132];   // feat rows: hl[r][k], stride 132
    int tid = threadIdx.x;
    int blk = xcd_swz(blockIdx.x, 128);             // 1024 blocks -> chunk 128

    // ---- build phase 1: issue 4 independent atomicAdd chains up front
    int eidx = blk * 256 + tid;
    const int4* e4 = (const int4*)ei;
    int4 s = e4[eidx];
    int4 d = e4[NE / 4 + eidx];
    int t0 = atomicAdd(&cursor[d.x], 1);
    int t1 = atomicAdd(&cursor[d.y], 1);
    int t2 = atomicAdd(&cursor[d.z], 1);
    int t3 = atomicAdd(&cursor[d.w], 1);

    // ---- gemm staging
    for (int i = tid; i < 128 * 32; i += 256) {
        int k = i >> 5, c = i & 31;
        wl[c * 132 + k] = W0[i];
    }
    int base = blk * 64;
    const float* fsrc = feat + (size_t)base * 128;
    #pragma unroll
    for (int v = 0; v < 8; ++v) {
        int flat = v * 1024 + tid * 4;
        int rr = flat >> 7, kk = flat & 127;
        *(float4*)&hl[rr * 132 + kk] = *(const float4*)&fsrc[flat];
    }
    __syncthreads();

    // ---- gemm compute: thread = 4 rows x 2 cols
    int cg = tid & 15, rg = tid >> 4;
    int c0 = cg * 2, r0 = rg * 4;
    float acc[4][2] = {};
    #pragma unroll 2
    for (int k = 0; k < 128; k += 4) {
        float4 wa = *(const float4*)&wl[c0 * 132 + k];
        float4 wb = *(const float4*)&wl[(c0 + 1) * 132 + k];
        #pragma unroll
        for (int rr = 0; rr < 4; ++rr) {
            float4 hv = *(const float4*)&hl[(r0 + rr) * 132 + k];
            acc[rr][0] += hv.x * wa.x + hv.y * wa.y + hv.z * wa.z + hv.w * wa.w;
            acc[rr][1] += hv.x * wb.x + hv.y * wb.y + hv.z * wb.z + hv.w * wb.w;
        }
    }

    // ---- build phase 2: dependent ELL stores (atomic latency long gone)
    if (t0 < MAXD) ell[d.x * MAXD + t0] = s.x;
    if (t1 < MAXD) ell[d.y * MAXD + t1] = s.y;
    if (t2 < MAXD) ell[d.z * MAXD + t2] = s.z;
    if (t3 < MAXD) ell[d.w * MAXD + t3] = s.w;

    // ---- gemm epilogue
    #pragma unroll
    for (int rr = 0; rr < 4; ++rr) {
        int dd = base + r0 + rr;
        z1[dd * 32 + c0]     = acc[rr][0];
        z1[dd * 32 + c0 + 1] = acc[rr][1];
    }
}

// ---------------------------------------------------------------------------
// Gather helper: acc over neighbors with 8-deep load batching (ILP).
__device__ __forceinline__ float gather32(const int* __restrict__ row, int cnt,
                                          const float* __restrict__ zin, int c) {
    int i0 = row[c];
    float acc = 0.f;
    int m = cnt < 32 ? cnt : 32;
    int j = 0;
    for (; j + 8 <= m; j += 8) {
        int s0 = __shfl(i0, j, 32),     s1 = __shfl(i0, j + 1, 32);
        int s2 = __shfl(i0, j + 2, 32), s3 = __shfl(i0, j + 3, 32);
        int s4 = __shfl(i0, j + 4, 32), s5 = __shfl(i0, j + 5, 32);
        int s6 = __shfl(i0, j + 6, 32), s7 = __shfl(i0, j + 7, 32);
        float t0 = zin[s0 * 32 + c], t1 = zin[s1 * 32 + c];
        float t2 = zin[s2 * 32 + c], t3 = zin[s3 * 32 + c];
        float t4 = zin[s4 * 32 + c], t5 = zin[s5 * 32 + c];
        float t6 = zin[s6 * 32 + c], t7 = zin[s7 * 32 + c];
        acc += ((t0 + t1) + (t2 + t3)) + ((t4 + t5) + (t6 + t7));
    }
    for (; j + 2 <= m; j += 2) {
        int s0 = __shfl(i0, j, 32), s1 = __shfl(i0, j + 1, 32);
        float t0 = zin[s0 * 32 + c], t1 = zin[s1 * 32 + c];
        acc += t0 + t1;
    }
    for (; j < m; ++j) acc += zin[__shfl(i0, j, 32) * 32 + c];
    if (cnt > 32) {   // rare (P ~ 1e-4 per node)
        int i1 = row[32 + c];
        for (int j2 = 32; j2 < cnt; ++j2)
            acc += zin[__shfl(i1, j2 - 32, 32) * 32 + c];
    }
    return acc;
}

// ---------------------------------------------------------------------------
// Fused: agg = A*zin;  h = tanh((agg + zin + b)/deg);  znext = h @ Wn (32x32)
__global__ __launch_bounds__(256) void k_layer(const int* __restrict__ cursor,
                                               const int* __restrict__ ell,
                                               const float* __restrict__ zin,
                                               const float* __restrict__ degs,
                                               const float* __restrict__ bias,
                                               const float* __restrict__ Wn,
                                               float* __restrict__ hout,
                                               float* __restrict__ znext) {
    __shared__ float wt[32 * 36];    // W transposed: wt[c][k], stride 36 (16B aligned)
    __shared__ float hl[8][36];
    int tid = threadIdx.x;
    for (int i = tid; i < 1024; i += 256) {
        int k = i >> 5, c = i & 31;
        wt[c * 36 + k] = Wn[i];
    }
    int blk = xcd_swz(blockIdx.x, NN / 8 / 8);      // 8192 blocks -> chunk 1024
    int r = tid >> 5, c = tid & 31;
    int d = blk * 8 + r;
    int cnt = cursor[d]; if (cnt > MAXD) cnt = MAXD;
    const int* row = ell + (size_t)d * MAXD;
    float acc = gather32(row, cnt, zin, c);
    float val = tanhf((acc + zin[d * 32 + c] + bias[c]) / degs[d]);
    hout[d * 32 + c] = val;
    hl[r][c] = val;
    __syncthreads();
    const float* hrow = &hl[r][0];
    const float* wrow = wt + c * 36;
    float4 a4 = {0.f, 0.f, 0.f, 0.f};
    #pragma unroll
    for (int k = 0; k < 32; k += 4) {
        float4 hv = *(const float4*)&hrow[k];
        float4 wv = *(const float4*)&wrow[k];
        a4.x += hv.x * wv.x; a4.y += hv.y * wv.y;
        a4.z += hv.z * wv.z; a4.w += hv.w * wv.w;
    }
    znext[d * 32 + c] = (a4.x + a4.y) + (a4.z + a4.w);
}

// ---------------------------------------------------------------------------
// Layer 3 variant: znext is 1-wide (z4 = h3 @ W3), done with a shuffle reduce.
__global__ __launch_bounds__(256) void k_layer3(const int* __restrict__ cursor,
                                                const int* __restrict__ ell,
                                                const float* __restrict__ zin,
                                                const float* __restrict__ degs,
                                                const float* __restrict__ bias,
                                                const float* __restrict__ W3,
                                                float* __restrict__ hout,
                                                float* __restrict__ z4) {
    int tid = threadIdx.x;
    int blk = xcd_swz(blockIdx.x, NN / 8 / 8);
    int r = tid >> 5, c = tid & 31;
    int d = blk * 8 + r;
    int cnt = cursor[d]; if (cnt > MAXD) cnt = MAXD;
    const int* row = ell + (size_t)d * MAXD;
    float acc = gather32(row, cnt, zin, c);
    float val = tanhf((acc + zin[d * 32 + c] + bias[c]) / degs[d]);
    hout[d * 32 + c] = val;
    float v = val * W3[c];
    #pragma unroll
    for (int off = 16; off; off >>= 1) v += __shfl_xor(v, off, 32);
    if (c == 0) z4[d] = v;
}

// ---------------------------------------------------------------------------
// Fused: layer-4 gather (1-wide) -> h4; msg=[h1 h2 h3 h4]; phi=relu(msg@phiW+b);
// per-graph partial sum -> one atomicAdd set per block.
__global__ __launch_bounds__(256) void k_phi(const int* __restrict__ cursor,
                                             const int* __restrict__ ell,
                                             const float* __restrict__ z4,
                                             const float* __restrict__ degs,
                                             const float* __restrict__ b3,
                                             const float* __restrict__ h1,
                                             const float* __restrict__ h2,
                                             const float* __restrict__ h3,
                                             const float* __restrict__ phiW,
                                             const float* __restrict__ phib,
                                             float* __restrict__ summed) {
    __shared__ float pl[30 * 100];   // phiW transposed: pl[c][j], stride 100 (16B aligned)
    __shared__ float ml[8 * 100];    // msg rows, stride 100
    __shared__ float part[4][32];
    int tid = threadIdx.x;
    for (int i = tid; i < 30 * 97; i += 256) {
        int cc = i / 97, jj = i - cc * 97;
        pl[cc * 100 + jj] = phiW[jj * 30 + cc];
    }
    int blk = xcd_swz(blockIdx.x, NN / 8 / 8);
    int r = tid >> 5, c = tid & 31;
    int d = blk * 8 + r;
    int g = d >> 11;
    int cnt = cursor[d]; if (cnt > MAXD) cnt = MAXD;
    const int* row = ell + (size_t)d * MAXD;
    float acc = 0.f;
    for (int j = c; j < cnt; j += 32) acc += z4[row[j]];
    #pragma unroll
    for (int off = 16; off; off >>= 1) acc += __shfl_xor(acc, off, 32);
    float h4 = tanhf((acc + z4[d] + b3[0]) / degs[d]);   // uniform across the 32-lane group
    ml[r * 100 + c]      = h1[d * 32 + c];
    ml[r * 100 + 32 + c] = h2[d * 32 + c];
    ml[r * 100 + 64 + c] = h3[d * 32 + c];
    if (c == 0) ml[r * 100 + 96] = h4;
    __syncthreads();
    float s = 0.f;
    if (c < 30) {
        const float* mrow = ml + r * 100;
        const float* prow = pl + c * 100;
        float4 a4 = {0.f, 0.f, 0.f, 0.f};
        #pragma unroll
        for (int j = 0; j < 96; j += 4) {
            float4 mv = *(const float4*)&mrow[j];
            float4 pv = *(const float4*)&prow[j];
            a4.x += mv.x * pv.x; a4.y += mv.y * pv.y;
            a4.z += mv.z * pv.z; a4.w += mv.w * pv.w;
        }
        s = (a4.x + a4.y) + (a4.z + a4.w) + mrow[96] * prow[96] + phib[c];
        s = fmaxf(s, 0.f);
    }
    s += __shfl_down(s, 32);                 // rows pair-summed within each wave
    int wave = tid >> 6;
    if ((tid & 63) < 32) part[wave][tid & 31] = s;
    __syncthreads();
    if (tid < 32) {
        float tot = part[0][tid] + part[1][tid] + part[2][tid] + part[3][tid];
        if (tid < 30) atomicAdd(&summed[g * 30 + tid], tot);
    }
}

// ---------------------------------------------------------------------------
// out = summed @ rhoW + rhob   (32x30 @ 30x32)
__global__ __launch_bounds__(1024) void k_rho(const float* __restrict__ summed,
                                              const float* __restrict__ rhoW,
                                              const float* __restrict__ rhob,
                                              float* __restrict__ out) {
    int tid = threadIdx.x;
    int b = tid >> 5, o = tid & 31;
    float s = rhob[o];
    #pragma unroll
    for (int k = 0; k < 30; ++k) s += summed[b * 30 + k] * rhoW[k * 32 + o];
    out[tid] = s;
}

// ---------------------------------------------------------------------------
extern "C" void kernel_launch(void* const* d_in, const int* in_sizes, int n_in,
                              void* d_out, int out_size, void* d_ws, size_t ws_size,
                              hipStream_t stream) {
    const float* feat = (const float*)d_in[0];
    const float* degs = (const float*)d_in[1];
    const int*   ei   = (const int*)d_in[2];
    const float* W0   = (const float*)d_in[3];
    const float* b0   = (const float*)d_in[4];
    const float* W1   = (const float*)d_in[5];
    const float* b1   = (const float*)d_in[6];
    const float* W2   = (const float*)d_in[7];
    const float* b2   = (const float*)d_in[8];
    const float* W3   = (const float*)d_in[9];
    const float* b3   = (const float*)d_in[10];
    const float* phiW = (const float*)d_in[11];
    const float* phib = (const float*)d_in[12];
    const float* rhoW = (const float*)d_in[13];
    const float* rhob = (const float*)d_in[14];

    char* ws = (char*)d_ws;
    int*   cursor = (int*)(ws + WS_CURSOR);
    float* summed = (float*)(ws + WS_SUMMED);
    int*   ell    = (int*)(ws + WS_ELL);
    float* za     = (float*)(ws + WS_ZA);
    float* zb     = (float*)(ws + WS_ZB);
    float* h1     = (float*)(ws + WS_H1);
    float* h2     = (float*)(ws + WS_H2);
    float* h3     = (float*)(ws + WS_H3);
    float* z4     = (float*)(ws + WS_Z4);
    float* out    = (float*)d_out;

    // zero cursor + summed (ws is poisoned to 0xAA before every launch)
    hipMemsetAsync(ws, 0, WS_SUMMED + NG * 30 * 4, stream);

    k_gb    <<<NN / 64, 256, 0, stream>>>(feat, W0, za, ei, cursor, ell);
    k_layer <<<NN / 8, 256, 0, stream>>>(cursor, ell, za, degs, b0, W1, h1, zb);
    k_layer <<<NN / 8, 256, 0, stream>>>(cursor, ell, zb, degs, b1, W2, h2, za);
    k_layer3<<<NN / 8, 256, 0, stream>>>(cursor, ell, za, degs, b2, W3, h3, z4);
    k_phi   <<<NN / 8, 256, 0, stream>>>(cursor, ell, z4, degs, b3, h1, h2, h3, phiW, phib, summed);
    k_rho   <<<1, 1024, 0, stream>>>(summed, rhoW, rhob, out);
}

// Round 7
// 295.019 us; speedup vs baseline: 1.0106x; 1.0106x over previous
//
#include <hip/hip_runtime.h>
#include <hip/hip_bf16.h>

// Problem constants (fixed by the reference harness)
#define NN 65536            // total nodes
#define NE (NN * 16)        // total edges = 1,048,576
#define NG 32               // graphs

// Workspace layout (bytes)
#define WS_CURSOR 0                         // NN ints   = 256 KB
#define WS_SUMMED 262144                    // NG*30 f32
#define WS_ROWPTR 278528                    // NN ints   = 256 KB (272 KB aligned start)
#define WS_ELL    1048576                   // CSR adjacency, NE ints = 4 MB (16 MB reserved)
#define WS_ZA     (WS_ELL + NN * 64 * 4)
#define WS_ZB     (WS_ZA + NN * 32 * 4)
#define WS_H1     (WS_ZB + NN * 32 * 4)
#define WS_H2     (WS_H1 + NN * 32 * 4)
#define WS_H3     (WS_H2 + NN * 32 * 4)
#define WS_Z4     (WS_H3 + NN * 32 * 4)     // NN f32

// XCD-affine swizzle: 8 XCDs, round-robin dispatch (blockIdx % 8).
__device__ __forceinline__ int xcd_swz(int b, int chunk) {
    return (b & 7) * chunk + (b >> 3);
}

__device__ __forceinline__ float ftanh(float x) {
    float xc = fmaxf(fminf(x, 15.f), -15.f);
    float e = __expf(2.f * xc);
    return (e - 1.f) * __builtin_amdgcn_rcpf(e + 1.f);
}

// ---------------------------------------------------------------------------
// Per-graph exclusive scan of (deg-1) -> CSR rowptr. 32 blocks x 1024 threads.
__global__ __launch_bounds__(1024) void k_scan(const float* __restrict__ degs,
                                               int* __restrict__ rowptr) {
    __shared__ int part[1024];
    int g = blockIdx.x, t = threadIdx.x;
    int base = g * 2048;
    int c0 = (int)degs[base + 2 * t] - 1;
    int c1 = (int)degs[base + 2 * t + 1] - 1;
    int sum = c0 + c1;
    part[t] = sum;
    __syncthreads();
    for (int off = 1; off < 1024; off <<= 1) {
        int v = (t >= off) ? part[t - off] : 0;
        __syncthreads();
        part[t] += v;
        __syncthreads();
    }
    int excl = part[t] - sum;
    int gbase = g * 32768;              // 32768 edges per graph exactly
    rowptr[base + 2 * t]     = gbase + excl;
    rowptr[base + 2 * t + 1] = gbase + excl + c0;
}

// ---------------------------------------------------------------------------
// Build CSR adjacency keyed by dst: csr[rowptr[dst] + slot] = src. 4 edges/thread.
__global__ __launch_bounds__(256) void k_build(const int* __restrict__ ei,
                                               const int* __restrict__ rowptr,
                                               int* __restrict__ cursor,
                                               int* __restrict__ csr) {
    int blk = xcd_swz(blockIdx.x, 128);             // 1024 blocks -> chunk 128
    int idx = blk * 256 + threadIdx.x;
    const int4* e4 = (const int4*)ei;
    int4 s = e4[idx];
    int4 d = e4[NE / 4 + idx];
    int r0 = rowptr[d.x], r1 = rowptr[d.y], r2 = rowptr[d.z], r3 = rowptr[d.w];
    int t0 = atomicAdd(&cursor[d.x], 1);
    int t1 = atomicAdd(&cursor[d.y], 1);
    int t2 = atomicAdd(&cursor[d.z], 1);
    int t3 = atomicAdd(&cursor[d.w], 1);
    csr[r0 + t0] = s.x;                              // capacity exact: no guard
    csr[r1 + t1] = s.y;
    csr[r2 + t2] = s.z;
    csr[r3 + t3] = s.w;
}

// ---------------------------------------------------------------------------
// z1 = feat (N x 128) @ W0 (128 x 32).  64 rows/block, thread = 4 rows x 2 cols.
__global__ __launch_bounds__(256) void k_gemm1(const float* __restrict__ feat,
                                               const float* __restrict__ W0,
                                               float* __restrict__ z1) {
    __shared__ float wl[32 * 132];
    __shared__ float hl[64 * 132];
    int tid = threadIdx.x;
    for (int i = tid; i < 128 * 32; i += 256) {
        int k = i >> 5, c = i & 31;
        wl[c * 132 + k] = W0[i];
    }
    int base = blockIdx.x * 64;
    const float* fsrc = feat + (size_t)base * 128;
    #pragma unroll
    for (int v = 0; v < 8; ++v) {
        int flat = v * 1024 + tid * 4;
        int rr = flat >> 7, kk = flat & 127;
        *(float4*)&hl[rr * 132 + kk] = *(const float4*)&fsrc[flat];
    }
    __syncthreads();
    int cg = tid & 15, rg = tid >> 4;
    int c0 = cg * 2, r0 = rg * 4;
    float acc[4][2] = {};
    #pragma unroll 2
    for (int k = 0; k < 128; k += 4) {
        float4 wa = *(const float4*)&wl[c0 * 132 + k];
        float4 wb = *(const float4*)&wl[(c0 + 1) * 132 + k];
        #pragma unroll
        for (int rr = 0; rr < 4; ++rr) {
            float4 hv = *(const float4*)&hl[(r0 + rr) * 132 + k];
            acc[rr][0] += hv.x * wa.x + hv.y * wa.y + hv.z * wa.z + hv.w * wa.w;
            acc[rr][1] += hv.x * wb.x + hv.y * wb.y + hv.z * wb.z + hv.w * wb.w;
        }
    }
    #pragma unroll
    for (int rr = 0; rr < 4; ++rr) {
        int d = base + r0 + rr;
        z1[d * 32 + c0]     = acc[rr][0];
        z1[d * 32 + c0 + 1] = acc[rr][1];
    }
}

// ---------------------------------------------------------------------------
// float4 gather: 8-lane node group, lane q handles columns 4q..4q+3.
// 8-deep load batches; indices distributed via width-8 shuffles.
#define GB8(iv) do {                                                           \
    int s0=__shfl((iv),0,8), s1=__shfl((iv),1,8), s2=__shfl((iv),2,8), s3=__shfl((iv),3,8); \
    int s4=__shfl((iv),4,8), s5=__shfl((iv),5,8), s6=__shfl((iv),6,8), s7=__shfl((iv),7,8); \
    float4 v0=*(const float4*)&zin[(size_t)s0*32+q4];                          \
    float4 v1=*(const float4*)&zin[(size_t)s1*32+q4];                          \
    float4 v2=*(const float4*)&zin[(size_t)s2*32+q4];                          \
    float4 v3=*(const float4*)&zin[(size_t)s3*32+q4];                          \
    float4 v4=*(const float4*)&zin[(size_t)s4*32+q4];                          \
    float4 v5=*(const float4*)&zin[(size_t)s5*32+q4];                          \
    float4 v6=*(const float4*)&zin[(size_t)s6*32+q4];                          \
    float4 v7=*(const float4*)&zin[(size_t)s7*32+q4];                          \
    acc.x += ((v0.x+v1.x)+(v2.x+v3.x)) + ((v4.x+v5.x)+(v6.x+v7.x));            \
    acc.y += ((v0.y+v1.y)+(v2.y+v3.y)) + ((v4.y+v5.y)+(v6.y+v7.y));            \
    acc.z += ((v0.z+v1.z)+(v2.z+v3.z)) + ((v4.z+v5.z)+(v6.z+v7.z));            \
    acc.w += ((v0.w+v1.w)+(v2.w+v3.w)) + ((v4.w+v5.w)+(v6.w+v7.w));            \
} while (0)

__device__ __forceinline__ float4 gatherf4(const int* __restrict__ row, int cnt,
                                           const float* __restrict__ zin,
                                           int q4, float4 acc) {
    int q = q4 >> 2;
    int i0 = row[q], i1 = row[8 + q], i2 = row[16 + q], i3 = row[24 + q];
    int m = cnt < 32 ? cnt : 32;
    if (m >= 8)  GB8(i0);
    if (m >= 16) GB8(i1);
    if (m >= 24) GB8(i2);
    if (m >= 32) GB8(i3);
    int done = m & ~7;
    if (done < m) {
        int ivr = (done == 0) ? i0 : (done == 8) ? i1 : (done == 16) ? i2 : i3;
        for (int j = done; j < m; ++j) {
            int s = __shfl(ivr, j - done, 8);
            float4 v = *(const float4*)&zin[(size_t)s * 32 + q4];
            acc.x += v.x; acc.y += v.y; acc.z += v.z; acc.w += v.w;
        }
    }
    for (int j = 32; j < cnt; ++j) {                 // astronomically rare
        int s = row[j];
        float4 v = *(const float4*)&zin[(size_t)s * 32 + q4];
        acc.x += v.x; acc.y += v.y; acc.z += v.z; acc.w += v.w;
    }
    return acc;
}

// ---------------------------------------------------------------------------
// Fused: agg = A*zin (+self); h = ftanh((agg+b)/deg); znext = h @ Wn (32x32).
// 32 nodes/block, node = 8 lanes.
__global__ __launch_bounds__(256) void k_layer(const int* __restrict__ rowptr,
                                               const float* __restrict__ degs,
                                               const int* __restrict__ csr,
                                               const float* __restrict__ zin,
                                               const float* __restrict__ bias,
                                               const float* __restrict__ Wn,
                                               float* __restrict__ hout,
                                               float* __restrict__ znext) {
    __shared__ float wt[32 * 36];    // W transposed: wt[c][k]
    __shared__ float hl[32 * 36];
    int tid = threadIdx.x;
    for (int i = tid; i < 1024; i += 256) {
        int k = i >> 5, c = i & 31;
        wt[c * 36 + k] = Wn[i];
    }
    int blk = xcd_swz(blockIdx.x, 256);             // 2048 blocks -> chunk 256
    int r = tid >> 3, q4 = (tid & 7) * 4;
    int d = blk * 32 + r;
    float degv = degs[d];
    int cnt = (int)degv - 1;
    const int* row = csr + rowptr[d];
    float4 acc = *(const float4*)&zin[(size_t)d * 32 + q4];    // self term
    acc = gatherf4(row, cnt, zin, q4, acc);
    float4 b4 = *(const float4*)&bias[q4];
    float rdeg = __builtin_amdgcn_rcpf(degv);
    float4 val;
    val.x = ftanh((acc.x + b4.x) * rdeg);
    val.y = ftanh((acc.y + b4.y) * rdeg);
    val.z = ftanh((acc.z + b4.z) * rdeg);
    val.w = ftanh((acc.w + b4.w) * rdeg);
    *(float4*)&hout[(size_t)d * 32 + q4] = val;
    *(float4*)&hl[r * 36 + q4] = val;
    __syncthreads();
    #pragma unroll
    for (int it = 0; it < 4; ++it) {
        int wid = tid + it * 256;
        int n = wid >> 5, c = wid & 31;
        const float* hrow = &hl[n * 36];
        const float* wrow = &wt[c * 36];
        float4 a4 = {0.f, 0.f, 0.f, 0.f};
        #pragma unroll
        for (int k = 0; k < 32; k += 4) {
            float4 hv = *(const float4*)&hrow[k];
            float4 wv = *(const float4*)&wrow[k];
            a4.x += hv.x * wv.x; a4.y += hv.y * wv.y;
            a4.z += hv.z * wv.z; a4.w += hv.w * wv.w;
        }
        znext[(size_t)(blk * 32 + n) * 32 + c] = (a4.x + a4.y) + (a4.z + a4.w);
    }
}

// ---------------------------------------------------------------------------
// Layer-3 variant: z4 = h3 @ W3 is 1-wide -> in-group reduce, no LDS phase.
__global__ __launch_bounds__(256) void k_layer3(const int* __restrict__ rowptr,
                                                const float* __restrict__ degs,
                                                const int* __restrict__ csr,
                                                const float* __restrict__ zin,
                                                const float* __restrict__ bias,
                                                const float* __restrict__ W3,
                                                float* __restrict__ hout,
                                                float* __restrict__ z4) {
    int tid = threadIdx.x;
    int blk = xcd_swz(blockIdx.x, 256);
    int r = tid >> 3, q4 = (tid & 7) * 4;
    int d = blk * 32 + r;
    float degv = degs[d];
    int cnt = (int)degv - 1;
    const int* row = csr + rowptr[d];
    float4 acc = *(const float4*)&zin[(size_t)d * 32 + q4];
    acc = gatherf4(row, cnt, zin, q4, acc);
    float4 b4 = *(const float4*)&bias[q4];
    float rdeg = __builtin_amdgcn_rcpf(degv);
    float4 val;
    val.x = ftanh((acc.x + b4.x) * rdeg);
    val.y = ftanh((acc.y + b4.y) * rdeg);
    val.z = ftanh((acc.z + b4.z) * rdeg);
    val.w = ftanh((acc.w + b4.w) * rdeg);
    *(float4*)&hout[(size_t)d * 32 + q4] = val;
    float4 w4 = *(const float4*)&W3[q4];
    float v = (val.x * w4.x + val.y * w4.y) + (val.z * w4.z + val.w * w4.w);
    v += __shfl_xor(v, 1, 8);
    v += __shfl_xor(v, 2, 8);
    v += __shfl_xor(v, 4, 8);
    if ((tid & 7) == 0) z4[d] = v;
}

// ---------------------------------------------------------------------------
// Fused: layer-4 gather (1-wide) -> h4; msg=[h1 h2 h3 h4]; phi=relu(msg@phiW+b);
// per-graph partial sum -> one atomicAdd set per block. 16 nodes/block, 512 thr.
__global__ __launch_bounds__(512) void k_phi(const int* __restrict__ rowptr,
                                             const float* __restrict__ degs,
                                             const int* __restrict__ csr,
                                             const float* __restrict__ z4,
                                             const float* __restrict__ b3,
                                             const float* __restrict__ h1,
                                             const float* __restrict__ h2,
                                             const float* __restrict__ h3,
                                             const float* __restrict__ phiW,
                                             const float* __restrict__ phib,
                                             float* __restrict__ summed) {
    __shared__ float pl[30 * 100];   // phiW transposed: pl[c][j]
    __shared__ float ml[16 * 100];   // msg rows
    __shared__ float part[8][32];
    int tid = threadIdx.x;
    for (int i = tid; i < 30 * 97; i += 512) {
        int cc = i / 97, jj = i - cc * 97;
        pl[cc * 100 + jj] = phiW[jj * 30 + cc];
    }
    int blk = xcd_swz(blockIdx.x, 512);             // 4096 blocks -> chunk 512
    int r = tid >> 5, c = tid & 31;
    int d = blk * 16 + r;
    int g = d >> 11;
    float degv = degs[d];
    int cnt = (int)degv - 1;
    const int* row = csr + rowptr[d];
    float acc = 0.f;
    for (int j = c; j < cnt; j += 32) acc += z4[row[j]];
    #pragma unroll
    for (int off = 16; off; off >>= 1) acc += __shfl_xor(acc, off, 32);
    float h4 = ftanh((acc + z4[d] + b3[0]) * __builtin_amdgcn_rcpf(degv));
    ml[r * 100 + c]      = h1[(size_t)d * 32 + c];
    ml[r * 100 + 32 + c] = h2[(size_t)d * 32 + c];
    ml[r * 100 + 64 + c] = h3[(size_t)d * 32 + c];
    if (c == 0) ml[r * 100 + 96] = h4;
    __syncthreads();
    float s = 0.f;
    if (c < 30) {
        const float* mrow = ml + r * 100;
        const float* prow = pl + c * 100;
        float4 a4 = {0.f, 0.f, 0.f, 0.f};
        #pragma unroll
        for (int j = 0; j < 96; j += 4) {
            float4 mv = *(const float4*)&mrow[j];
            float4 pv = *(const float4*)&prow[j];
            a4.x += mv.x * pv.x; a4.y += mv.y * pv.y;
            a4.z += mv.z * pv.z; a4.w += mv.w * pv.w;
        }
        s = (a4.x + a4.y) + (a4.z + a4.w) + mrow[96] * prow[96] + phib[c];
        s = fmaxf(s, 0.f);
    }
    s += __shfl_down(s, 32);                 // node pair within each wave
    int wave = tid >> 6;
    if ((tid & 63) < 32) part[wave][tid & 31] = s;
    __syncthreads();
    if (tid < 32) {
        float tot = 0.f;
        #pragma unroll
        for (int w = 0; w < 8; ++w) tot += part[w][tid];
        if (tid < 30) atomicAdd(&summed[g * 30 + tid], tot);
    }
}

// ---------------------------------------------------------------------------
// out = summed @ rhoW + rhob   (32x30 @ 30x32)
__global__ __launch_bounds__(1024) void k_rho(const float* __restrict__ summed,
                                              const float* __restrict__ rhoW,
                                              const float* __restrict__ rhob,
                                              float* __restrict__ out) {
    int tid = threadIdx.x;
    int b = tid >> 5, o = tid & 31;
    float s = rhob[o];
    #pragma unroll
    for (int k = 0; k < 30; ++k) s += summed[b * 30 + k] * rhoW[k * 32 + o];
    out[tid] = s;
}

// ---------------------------------------------------------------------------
extern "C" void kernel_launch(void* const* d_in, const int* in_sizes, int n_in,
                              void* d_out, int out_size, void* d_ws, size_t ws_size,
                              hipStream_t stream) {
    const float* feat = (const float*)d_in[0];
    const float* degs = (const float*)d_in[1];
    const int*   ei   = (const int*)d_in[2];
    const float* W0   = (const float*)d_in[3];
    const float* b0   = (const float*)d_in[4];
    const float* W1   = (const float*)d_in[5];
    const float* b1   = (const float*)d_in[6];
    const float* W2   = (const float*)d_in[7];
    const float* b2   = (const float*)d_in[8];
    const float* W3   = (const float*)d_in[9];
    const float* b3   = (const float*)d_in[10];
    const float* phiW = (const float*)d_in[11];
    const float* phib = (const float*)d_in[12];
    const float* rhoW = (const float*)d_in[13];
    const float* rhob = (const float*)d_in[14];

    char* ws = (char*)d_ws;
    int*   cursor = (int*)(ws + WS_CURSOR);
    float* summed = (float*)(ws + WS_SUMMED);
    int*   rowptr = (int*)(ws + WS_ROWPTR);
    int*   csr    = (int*)(ws + WS_ELL);
    float* za     = (float*)(ws + WS_ZA);
    float* zb     = (float*)(ws + WS_ZB);
    float* h1     = (float*)(ws + WS_H1);
    float* h2     = (float*)(ws + WS_H2);
    float* h3     = (float*)(ws + WS_H3);
    float* z4     = (float*)(ws + WS_Z4);
    float* out    = (float*)d_out;

    // zero cursor + summed (ws is poisoned to 0xAA before every launch)
    hipMemsetAsync(ws, 0, WS_SUMMED + NG * 30 * 4, stream);

    k_scan  <<<NG, 1024, 0, stream>>>(degs, rowptr);
    k_build <<<NE / 1024, 256, 0, stream>>>(ei, rowptr, cursor, csr);
    k_gemm1 <<<NN / 64, 256, 0, stream>>>(feat, W0, za);
    k_layer <<<NN / 32, 256, 0, stream>>>(rowptr, degs, csr, za, b0, W1, h1, zb);
    k_layer <<<NN / 32, 256, 0, stream>>>(rowptr, degs, csr, zb, b1, W2, h2, za);
    k_layer3<<<NN / 32, 256, 0, stream>>>(rowptr, degs, csr, za, b2, W3, h3, z4);
    k_phi   <<<NN / 16, 512, 0, stream>>>(rowptr, degs, csr, z4, b3, h1, h2, h3, phiW, phib, summed);
    k_rho   <<<1, 1024, 0, stream>>>(summed, rhoW, rhob, out);
}

// Round 9
// 293.158 us; speedup vs baseline: 1.0170x; 1.0063x over previous
//
#include <hip/hip_runtime.h>
#include <hip/hip_bf16.h>

// Problem constants (fixed by the reference harness)
#define NN 65536            // total nodes
#define NE (NN * 16)        // total edges = 1,048,576
#define NG 32               // graphs
#define MAXD 64             // ELL slots per node (max in-degree ~45 for Poisson(16))

// Workspace layout (bytes)
#define WS_CURSOR 0                         // NN ints   = 256 KB
#define WS_SUMMED 262144                    // NG*30 f32
#define WS_ELL    1048576                   // ELL ushort adjacency: NN*64*2 = 8 MB
#define WS_ZA     (WS_ELL + NN * MAXD * 2)
#define WS_ZB     (WS_ZA + NN * 32 * 4)
#define WS_H1     (WS_ZB + NN * 32 * 4)
#define WS_H2     (WS_H1 + NN * 32 * 4)
#define WS_H3     (WS_H2 + NN * 32 * 4)
#define WS_Z4     (WS_H3 + NN * 32 * 4)     // NN f32

// XCD-affine swizzle: 8 XCDs, round-robin dispatch (blockIdx % 8).
__device__ __forceinline__ int xcd_swz(int b, int chunk) {
    return (b & 7) * chunk + (b >> 3);
}

__device__ __forceinline__ float ftanh(float x) {
    float xc = fmaxf(fminf(x, 15.f), -15.f);
    float e = __expf(2.f * xc);
    return (e - 1.f) * __builtin_amdgcn_rcpf(e + 1.f);
}

// ---------------------------------------------------------------------------
// Build ELL (ushort in-graph src offsets): ell[dst*64+slot] = src & 2047.
// 4 independent atomic->store chains per thread (round-3 proven shape).
__global__ __launch_bounds__(256) void k_build(const int* __restrict__ ei,
                                               int* __restrict__ cursor,
                                               unsigned short* __restrict__ ell) {
    int blk = xcd_swz(blockIdx.x, 128);             // 1024 blocks -> chunk 128
    int idx = blk * 256 + threadIdx.x;
    const int4* e4 = (const int4*)ei;
    int4 s = e4[idx];
    int4 d = e4[NE / 4 + idx];
    int t0 = atomicAdd(&cursor[d.x], 1);
    int t1 = atomicAdd(&cursor[d.y], 1);
    int t2 = atomicAdd(&cursor[d.z], 1);
    int t3 = atomicAdd(&cursor[d.w], 1);
    if (t0 < MAXD) ell[d.x * MAXD + t0] = (unsigned short)(s.x & 2047);
    if (t1 < MAXD) ell[d.y * MAXD + t1] = (unsigned short)(s.y & 2047);
    if (t2 < MAXD) ell[d.z * MAXD + t2] = (unsigned short)(s.z & 2047);
    if (t3 < MAXD) ell[d.w * MAXD + t3] = (unsigned short)(s.w & 2047);
}

// ---------------------------------------------------------------------------
// z1 = feat (N x 128) @ W0 (128 x 32).  64 rows/block, thread = 4 rows x 2 cols.
__global__ __launch_bounds__(256) void k_gemm1(const float* __restrict__ feat,
                                               const float* __restrict__ W0,
                                               float* __restrict__ z1) {
    __shared__ float wl[32 * 132];
    __shared__ float hl[64 * 132];
    int tid = threadIdx.x;
    for (int i = tid; i < 128 * 32; i += 256) {
        int k = i >> 5, c = i & 31;
        wl[c * 132 + k] = W0[i];
    }
    int base = blockIdx.x * 64;
    const float* fsrc = feat + (size_t)base * 128;
    #pragma unroll
    for (int v = 0; v < 8; ++v) {
        int flat = v * 1024 + tid * 4;
        int rr = flat >> 7, kk = flat & 127;
        *(float4*)&hl[rr * 132 + kk] = *(const float4*)&fsrc[flat];
    }
    __syncthreads();
    int cg = tid & 15, rg = tid >> 4;
    int c0 = cg * 2, r0 = rg * 4;
    float acc[4][2] = {};
    #pragma unroll 2
    for (int k = 0; k < 128; k += 4) {
        float4 wa = *(const float4*)&wl[c0 * 132 + k];
        float4 wb = *(const float4*)&wl[(c0 + 1) * 132 + k];
        #pragma unroll
        for (int rr = 0; rr < 4; ++rr) {
            float4 hv = *(const float4*)&hl[(r0 + rr) * 132 + k];
            acc[rr][0] += hv.x * wa.x + hv.y * wa.y + hv.z * wa.z + hv.w * wa.w;
            acc[rr][1] += hv.x * wb.x + hv.y * wb.y + hv.z * wb.z + hv.w * wb.w;
        }
    }
    #pragma unroll
    for (int rr = 0; rr < 4; ++rr) {
        int d = base + r0 + rr;
        z1[d * 32 + c0]     = acc[rr][0];
        z1[d * 32 + c0 + 1] = acc[rr][1];
    }
}

// ---------------------------------------------------------------------------
// float4 gather: 8-lane node group, lane q handles columns 4q..4q+3.
// zg = zin + graph_base*32 (so ushort offsets index within the graph).
#define GB8(iv) do {                                                           \
    int s0=__shfl((iv),0,8), s1=__shfl((iv),1,8), s2=__shfl((iv),2,8), s3=__shfl((iv),3,8); \
    int s4=__shfl((iv),4,8), s5=__shfl((iv),5,8), s6=__shfl((iv),6,8), s7=__shfl((iv),7,8); \
    float4 v0=*(const float4*)&zg[(size_t)s0*32+q4];                           \
    float4 v1=*(const float4*)&zg[(size_t)s1*32+q4];                           \
    float4 v2=*(const float4*)&zg[(size_t)s2*32+q4];                           \
    float4 v3=*(const float4*)&zg[(size_t)s3*32+q4];                           \
    float4 v4=*(const float4*)&zg[(size_t)s4*32+q4];                           \
    float4 v5=*(const float4*)&zg[(size_t)s5*32+q4];                           \
    float4 v6=*(const float4*)&zg[(size_t)s6*32+q4];                           \
    float4 v7=*(const float4*)&zg[(size_t)s7*32+q4];                           \
    acc.x += ((v0.x+v1.x)+(v2.x+v3.x)) + ((v4.x+v5.x)+(v6.x+v7.x));            \
    acc.y += ((v0.y+v1.y)+(v2.y+v3.y)) + ((v4.y+v5.y)+(v6.y+v7.y));            \
    acc.z += ((v0.z+v1.z)+(v2.z+v3.z)) + ((v4.z+v5.z)+(v6.z+v7.z));            \
    acc.w += ((v0.w+v1.w)+(v2.w+v3.w)) + ((v4.w+v5.w)+(v6.w+v7.w));            \
} while (0)

__device__ __forceinline__ float4 gatherf4(const unsigned short* __restrict__ row,
                                           int cnt, const float* __restrict__ zg,
                                           int q4, float4 acc) {
    int q = q4 >> 2;
    int i0 = row[q], i1 = row[8 + q], i2 = row[16 + q], i3 = row[24 + q];
    int m = cnt < 32 ? cnt : 32;
    if (m >= 8)  GB8(i0);
    if (m >= 16) GB8(i1);
    if (m >= 24) GB8(i2);
    if (m >= 32) GB8(i3);
    int done = m & ~7;
    if (done < m) {
        int ivr = (done == 0) ? i0 : (done == 8) ? i1 : (done == 16) ? i2 : i3;
        for (int j = done; j < m; ++j) {
            int s = __shfl(ivr, j - done, 8);
            float4 v = *(const float4*)&zg[(size_t)s * 32 + q4];
            acc.x += v.x; acc.y += v.y; acc.z += v.z; acc.w += v.w;
        }
    }
    for (int j = 32; j < cnt && j < MAXD; ++j) {     // astronomically rare
        int s = row[j];
        float4 v = *(const float4*)&zg[(size_t)s * 32 + q4];
        acc.x += v.x; acc.y += v.y; acc.z += v.z; acc.w += v.w;
    }
    return acc;
}

// ---------------------------------------------------------------------------
// Fused: agg = A*zin (+self); h = ftanh((agg+b)/deg); znext = h @ Wn (32x32).
// 32 nodes/block, node = 8 lanes.
__global__ __launch_bounds__(256) void k_layer(const float* __restrict__ degs,
                                               const unsigned short* __restrict__ ell,
                                               const float* __restrict__ zin,
                                               const float* __restrict__ bias,
                                               const float* __restrict__ Wn,
                                               float* __restrict__ hout,
                                               float* __restrict__ znext) {
    __shared__ float wt[32 * 36];    // W transposed: wt[c][k]
    __shared__ float hl[32 * 36];
    int tid = threadIdx.x;
    for (int i = tid; i < 1024; i += 256) {
        int k = i >> 5, c = i & 31;
        wt[c * 36 + k] = Wn[i];
    }
    int blk = xcd_swz(blockIdx.x, 256);             // 2048 blocks -> chunk 256
    int r = tid >> 3, q4 = (tid & 7) * 4;
    int d = blk * 32 + r;
    const float* zg = zin + ((size_t)(d >> 11) << 11) * 32;   // graph base
    float degv = degs[d];
    int cnt = (int)degv - 1;
    const unsigned short* row = ell + (size_t)d * MAXD;
    float4 acc = *(const float4*)&zin[(size_t)d * 32 + q4];   // self term
    acc = gatherf4(row, cnt, zg, q4, acc);
    float4 b4 = *(const float4*)&bias[q4];
    float rdeg = __builtin_amdgcn_rcpf(degv);
    float4 val;
    val.x = ftanh((acc.x + b4.x) * rdeg);
    val.y = ftanh((acc.y + b4.y) * rdeg);
    val.z = ftanh((acc.z + b4.z) * rdeg);
    val.w = ftanh((acc.w + b4.w) * rdeg);
    *(float4*)&hout[(size_t)d * 32 + q4] = val;
    *(float4*)&hl[r * 36 + q4] = val;
    __syncthreads();
    #pragma unroll
    for (int it = 0; it < 4; ++it) {
        int wid = tid + it * 256;
        int n = wid >> 5, c = wid & 31;
        const float* hrow = &hl[n * 36];
        const float* wrow = &wt[c * 36];
        float4 a4 = {0.f, 0.f, 0.f, 0.f};
        #pragma unroll
        for (int k = 0; k < 32; k += 4) {
            float4 hv = *(const float4*)&hrow[k];
            float4 wv = *(const float4*)&wrow[k];
            a4.x += hv.x * wv.x; a4.y += hv.y * wv.y;
            a4.z += hv.z * wv.z; a4.w += hv.w * wv.w;
        }
        znext[(size_t)(blk * 32 + n) * 32 + c] = (a4.x + a4.y) + (a4.z + a4.w);
    }
}

// ---------------------------------------------------------------------------
// Layer-3 variant: z4 = h3 @ W3 is 1-wide -> in-group reduce, no LDS phase.
__global__ __launch_bounds__(256) void k_layer3(const float* __restrict__ degs,
                                                const unsigned short* __restrict__ ell,
                                                const float* __restrict__ zin,
                                                const float* __restrict__ bias,
                                                const float* __restrict__ W3,
                                                float* __restrict__ hout,
                                                float* __restrict__ z4) {
    int tid = threadIdx.x;
    int blk = xcd_swz(blockIdx.x, 256);
    int r = tid >> 3, q4 = (tid & 7) * 4;
    int d = blk * 32 + r;
    const float* zg = zin + ((size_t)(d >> 11) << 11) * 32;
    float degv = degs[d];
    int cnt = (int)degv - 1;
    const unsigned short* row = ell + (size_t)d * MAXD;
    float4 acc = *(const float4*)&zin[(size_t)d * 32 + q4];
    acc = gatherf4(row, cnt, zg, q4, acc);
    float4 b4 = *(const float4*)&bias[q4];
    float rdeg = __builtin_amdgcn_rcpf(degv);
    float4 val;
    val.x = ftanh((acc.x + b4.x) * rdeg);
    val.y = ftanh((acc.y + b4.y) * rdeg);
    val.z = ftanh((acc.z + b4.z) * rdeg);
    val.w = ftanh((acc.w + b4.w) * rdeg);
    *(float4*)&hout[(size_t)d * 32 + q4] = val;
    float4 w4 = *(const float4*)&W3[q4];
    float v = (val.x * w4.x + val.y * w4.y) + (val.z * w4.z + val.w * w4.w);
    v += __shfl_xor(v, 1, 8);
    v += __shfl_xor(v, 2, 8);
    v += __shfl_xor(v, 4, 8);
    if ((tid & 7) == 0) z4[d] = v;
}

// ---------------------------------------------------------------------------
// Fused: layer-4 gather (1-wide) -> h4; msg=[h1 h2 h3 h4]; phi=relu(msg@phiW+b);
// per-graph partial sum -> one atomicAdd set per block. 16 nodes/block, 512 thr.
__global__ __launch_bounds__(512) void k_phi(const float* __restrict__ degs,
                                             const unsigned short* __restrict__ ell,
                                             const float* __restrict__ z4,
                                             const float* __restrict__ b3,
                                             const float* __restrict__ h1,
                                             const float* __restrict__ h2,
                                             const float* __restrict__ h3,
                                             const float* __restrict__ phiW,
                                             const float* __restrict__ phib,
                                             float* __restrict__ summed) {
    __shared__ float pl[30 * 100];   // phiW transposed: pl[c][j]
    __shared__ float ml[16 * 100];   // msg rows
    __shared__ float part[8][32];
    int tid = threadIdx.x;
    for (int i = tid; i < 30 * 97; i += 512) {
        int cc = i / 97, jj = i - cc * 97;
        pl[cc * 100 + jj] = phiW[jj * 30 + cc];
    }
    int blk = xcd_swz(blockIdx.x, 512);             // 4096 blocks -> chunk 512
    int r = tid >> 5, c = tid & 31;
    int d = blk * 16 + r;
    int g = d >> 11;
    const float* z4g = z4 + ((size_t)g << 11);
    float degv = degs[d];
    int cnt = (int)degv - 1; if (cnt > MAXD) cnt = MAXD;
    const unsigned short* row = ell + (size_t)d * MAXD;
    float acc = 0.f;
    for (int j = c; j < cnt; j += 32) acc += z4g[row[j]];
    #pragma unroll
    for (int off = 16; off; off >>= 1) acc += __shfl_xor(acc, off, 32);
    float h4 = ftanh((acc + z4[d] + b3[0]) * __builtin_amdgcn_rcpf(degv));
    ml[r * 100 + c]      = h1[(size_t)d * 32 + c];
    ml[r * 100 + 32 + c] = h2[(size_t)d * 32 + c];
    ml[r * 100 + 64 + c] = h3[(size_t)d * 32 + c];
    if (c == 0) ml[r * 100 + 96] = h4;
    __syncthreads();
    float s = 0.f;
    if (c < 30) {
        const float* mrow = ml + r * 100;
        const float* prow = pl + c * 100;
        float4 a4 = {0.f, 0.f, 0.f, 0.f};
        #pragma unroll
        for (int j = 0; j < 96; j += 4) {
            float4 mv = *(const float4*)&mrow[j];
            float4 pv = *(const float4*)&prow[j];
            a4.x += mv.x * pv.x; a4.y += mv.y * pv.y;
            a4.z += mv.z * pv.z; a4.w += mv.w * pv.w;
        }
        s = (a4.x + a4.y) + (a4.z + a4.w) + mrow[96] * prow[96] + phib[c];
        s = fmaxf(s, 0.f);
    }
    s += __shfl_down(s, 32);                 // node pair within each wave
    int wave = tid >> 6;
    if ((tid & 63) < 32) part[wave][tid & 31] = s;
    __syncthreads();
    if (tid < 32) {
        float tot = 0.f;
        #pragma unroll
        for (int w = 0; w < 8; ++w) tot += part[w][tid];
        if (tid < 30) atomicAdd(&summed[g * 30 + tid], tot);
    }
}

// ---------------------------------------------------------------------------
// out = summed @ rhoW + rhob   (32x30 @ 30x32)
__global__ __launch_bounds__(1024) void k_rho(const float* __restrict__ summed,
                                              const float* __restrict__ rhoW,
                                              const float* __restrict__ rhob,
                                              float* __restrict__ out) {
    int tid = threadIdx.x;
    int b = tid >> 5, o = tid & 31;
    float s = rhob[o];
    #pragma unroll
    for (int k = 0; k < 30; ++k) s += summed[b * 30 + k] * rhoW[k * 32 + o];
    out[tid] = s;
}

// ---------------------------------------------------------------------------
extern "C" void kernel_launch(void* const* d_in, const int* in_sizes, int n_in,
                              void* d_out, int out_size, void* d_ws, size_t ws_size,
                              hipStream_t stream) {
    const float* feat = (const float*)d_in[0];
    const float* degs = (const float*)d_in[1];
    const int*   ei   = (const int*)d_in[2];
    const float* W0   = (const float*)d_in[3];
    const float* b0   = (const float*)d_in[4];
    const float* W1   = (const float*)d_in[5];
    const float* b1   = (const float*)d_in[6];
    const float* W2   = (const float*)d_in[7];
    const float* b2   = (const float*)d_in[8];
    const float* W3   = (const float*)d_in[9];
    const float* b3   = (const float*)d_in[10];
    const float* phiW = (const float*)d_in[11];
    const float* phib = (const float*)d_in[12];
    const float* rhoW = (const float*)d_in[13];
    const float* rhob = (const float*)d_in[14];

    char* ws = (char*)d_ws;
    int*            cursor = (int*)(ws + WS_CURSOR);
    float*          summed = (float*)(ws + WS_SUMMED);
    unsigned short* ell    = (unsigned short*)(ws + WS_ELL);
    float* za = (float*)(ws + WS_ZA);
    float* zb = (float*)(ws + WS_ZB);
    float* h1 = (float*)(ws + WS_H1);
    float* h2 = (float*)(ws + WS_H2);
    float* h3 = (float*)(ws + WS_H3);
    float* z4 = (float*)(ws + WS_Z4);
    float* out = (float*)d_out;

    // zero cursor + summed (ws is poisoned to 0xAA before every launch)
    hipMemsetAsync(ws, 0, WS_SUMMED + NG * 30 * 4, stream);

    k_build <<<NE / 1024, 256, 0, stream>>>(ei, cursor, ell);
    k_gemm1 <<<NN / 64, 256, 0, stream>>>(feat, W0, za);
    k_layer <<<NN / 32, 256, 0, stream>>>(degs, ell, za, b0, W1, h1, zb);
    k_layer <<<NN / 32, 256, 0, stream>>>(degs, ell, zb, b1, W2, h2, za);
    k_layer3<<<NN / 32, 256, 0, stream>>>(degs, ell, za, b2, W3, h3, z4);
    k_phi   <<<NN / 16, 512, 0, stream>>>(degs, ell, z4, b3, h1, h2, h3, phiW, phib, summed);
    k_rho   <<<1, 1024, 0, stream>>>(summed, rhoW, rhob, out);
}

// Round 11
// 259.864 us; speedup vs baseline: 1.1473x; 1.1281x over previous
//
#include <hip/hip_runtime.h>
#include <hip/hip_bf16.h>

// Problem constants (fixed by the reference harness)
#define NN 65536            // total nodes
#define NE (NN * 16)        // total edges = 1,048,576
#define NG 32               // graphs
#define MAXD 64             // ELL slots per node (max in-degree ~45 for Poisson(16))

// Workspace layout (bytes).  z/h buffers are bf16 (2B), z4 is f32.
#define WS_CURSOR 0                         // NN ints   = 256 KB
#define WS_SUMMED 262144                    // NG*30 f32
#define WS_ELL    1048576                   // int ELL: NN*64*4 = 16 MB
#define WS_ZA     (WS_ELL + NN * MAXD * 4)  // NN*32 bf16 = 4 MB
#define WS_ZB     (WS_ZA + NN * 32 * 2)
#define WS_H1     (WS_ZB + NN * 32 * 2)
#define WS_H2     (WS_H1 + NN * 32 * 2)
#define WS_H3     (WS_H2 + NN * 32 * 2)
#define WS_Z4     (WS_H3 + NN * 32 * 2)     // NN f32

typedef unsigned short bf16;

// XCD-affine swizzle: 8 XCDs, round-robin dispatch (blockIdx % 8).
__device__ __forceinline__ int xcd_swz(int b, int chunk) {
    return (b & 7) * chunk + (b >> 3);
}

__device__ __forceinline__ float ftanh(float x) {
    float xc = fmaxf(fminf(x, 15.f), -15.f);
    float e = __expf(2.f * xc);
    return (e - 1.f) * __builtin_amdgcn_rcpf(e + 1.f);
}

__device__ __forceinline__ float bf2f(bf16 u) {
    return __uint_as_float(((unsigned int)u) << 16);
}
__device__ __forceinline__ bf16 f2bf(float x) {
    unsigned int b = __float_as_uint(x);
    b += 0x7FFF + ((b >> 16) & 1);          // round to nearest even
    return (bf16)(b >> 16);
}

// ---------------------------------------------------------------------------
// Build int ELL: ell[dst*64+slot] = src.  EXACT round-3 shape (proven 56 us):
// 4 edges/thread, interleaved atomic->store chains, 1024 blocks, XCD swizzle.
__global__ __launch_bounds__(256) void k_build(const int* __restrict__ ei,
                                               int* __restrict__ cursor,
                                               int* __restrict__ ell) {
    int blk = xcd_swz(blockIdx.x, 128);             // 1024 blocks -> chunk 128
    int idx = blk * 256 + threadIdx.x;
    const int4* e4 = (const int4*)ei;
    int4 s = e4[idx];
    int4 d = e4[NE / 4 + idx];
    int t;
    t = atomicAdd(&cursor[d.x], 1); if (t < MAXD) ell[d.x * MAXD + t] = s.x;
    t = atomicAdd(&cursor[d.y], 1); if (t < MAXD) ell[d.y * MAXD + t] = s.y;
    t = atomicAdd(&cursor[d.z], 1); if (t < MAXD) ell[d.z * MAXD + t] = s.z;
    t = atomicAdd(&cursor[d.w], 1); if (t < MAXD) ell[d.w * MAXD + t] = s.w;
}

// ---------------------------------------------------------------------------
// z1 = feat (N x 128) @ W0 (128 x 32), output bf16.
__global__ __launch_bounds__(256) void k_gemm1(const float* __restrict__ feat,
                                               const float* __restrict__ W0,
                                               bf16* __restrict__ z1) {
    __shared__ float wl[32 * 132];
    __shared__ float hl[64 * 132];
    int tid = threadIdx.x;
    for (int i = tid; i < 128 * 32; i += 256) {
        int k = i >> 5, c = i & 31;
        wl[c * 132 + k] = W0[i];
    }
    int base = blockIdx.x * 64;
    const float* fsrc = feat + (size_t)base * 128;
    #pragma unroll
    for (int v = 0; v < 8; ++v) {
        int flat = v * 1024 + tid * 4;
        int rr = flat >> 7, kk = flat & 127;
        *(float4*)&hl[rr * 132 + kk] = *(const float4*)&fsrc[flat];
    }
    __syncthreads();
    int cg = tid & 15, rg = tid >> 4;
    int c0 = cg * 2, r0 = rg * 4;
    float acc[4][2] = {};
    #pragma unroll 2
    for (int k = 0; k < 128; k += 4) {
        float4 wa = *(const float4*)&wl[c0 * 132 + k];
        float4 wb = *(const float4*)&wl[(c0 + 1) * 132 + k];
        #pragma unroll
        for (int rr = 0; rr < 4; ++rr) {
            float4 hv = *(const float4*)&hl[(r0 + rr) * 132 + k];
            acc[rr][0] += hv.x * wa.x + hv.y * wa.y + hv.z * wa.z + hv.w * wa.w;
            acc[rr][1] += hv.x * wb.x + hv.y * wb.y + hv.z * wb.z + hv.w * wb.w;
        }
    }
    #pragma unroll
    for (int rr = 0; rr < 4; ++rr) {
        int d = base + r0 + rr;
        unsigned int pk = (unsigned int)f2bf(acc[rr][0]) |
                          ((unsigned int)f2bf(acc[rr][1]) << 16);
        *(unsigned int*)&z1[(size_t)d * 32 + c0] = pk;   // 4B-aligned pair
    }
}

// ---------------------------------------------------------------------------
// bf16 float4-style gather: 8-lane node group, lane q handles cols 4q..4q+3.
// One neighbor row = 64B = ONE cache line (8 lanes x 8B ushort4).
#define GB8(iv) do {                                                           \
    int s0=__shfl((iv),0,8), s1=__shfl((iv),1,8), s2=__shfl((iv),2,8), s3=__shfl((iv),3,8); \
    int s4=__shfl((iv),4,8), s5=__shfl((iv),5,8), s6=__shfl((iv),6,8), s7=__shfl((iv),7,8); \
    ushort4 v0=*(const ushort4*)&zin[(size_t)s0*32+q4];                        \
    ushort4 v1=*(const ushort4*)&zin[(size_t)s1*32+q4];                        \
    ushort4 v2=*(const ushort4*)&zin[(size_t)s2*32+q4];                        \
    ushort4 v3=*(const ushort4*)&zin[(size_t)s3*32+q4];                        \
    ushort4 v4=*(const ushort4*)&zin[(size_t)s4*32+q4];                        \
    ushort4 v5=*(const ushort4*)&zin[(size_t)s5*32+q4];                        \
    ushort4 v6=*(const ushort4*)&zin[(size_t)s6*32+q4];                        \
    ushort4 v7=*(const ushort4*)&zin[(size_t)s7*32+q4];                        \
    acc.x += ((bf2f(v0.x)+bf2f(v1.x))+(bf2f(v2.x)+bf2f(v3.x)))                 \
           + ((bf2f(v4.x)+bf2f(v5.x))+(bf2f(v6.x)+bf2f(v7.x)));                \
    acc.y += ((bf2f(v0.y)+bf2f(v1.y))+(bf2f(v2.y)+bf2f(v3.y)))                 \
           + ((bf2f(v4.y)+bf2f(v5.y))+(bf2f(v6.y)+bf2f(v7.y)));                \
    acc.z += ((bf2f(v0.z)+bf2f(v1.z))+(bf2f(v2.z)+bf2f(v3.z)))                 \
           + ((bf2f(v4.z)+bf2f(v5.z))+(bf2f(v6.z)+bf2f(v7.z)));                \
    acc.w += ((bf2f(v0.w)+bf2f(v1.w))+(bf2f(v2.w)+bf2f(v3.w)))                 \
           + ((bf2f(v4.w)+bf2f(v5.w))+(bf2f(v6.w)+bf2f(v7.w)));                \
} while (0)

__device__ __forceinline__ float4 gatherbf(const int* __restrict__ row, int cnt,
                                           const bf16* __restrict__ zin,
                                           int q4, float4 acc) {
    int q = q4 >> 2;
    int i0 = row[q], i1 = row[8 + q], i2 = row[16 + q], i3 = row[24 + q];
    int m = cnt < 32 ? cnt : 32;
    if (m >= 8)  GB8(i0);
    if (m >= 16) GB8(i1);
    if (m >= 24) GB8(i2);
    if (m >= 32) GB8(i3);
    int done = m & ~7;
    if (done < m) {
        int ivr = (done == 0) ? i0 : (done == 8) ? i1 : (done == 16) ? i2 : i3;
        for (int j = done; j < m; ++j) {
            int s = __shfl(ivr, j - done, 8);
            ushort4 v = *(const ushort4*)&zin[(size_t)s * 32 + q4];
            acc.x += bf2f(v.x); acc.y += bf2f(v.y);
            acc.z += bf2f(v.z); acc.w += bf2f(v.w);
        }
    }
    for (int j = 32; j < cnt && j < MAXD; ++j) {     // astronomically rare
        int s = row[j];
        ushort4 v = *(const ushort4*)&zin[(size_t)s * 32 + q4];
        acc.x += bf2f(v.x); acc.y += bf2f(v.y);
        acc.z += bf2f(v.z); acc.w += bf2f(v.w);
    }
    return acc;
}

// ---------------------------------------------------------------------------
// Fused: agg = A*zin (+self); h = ftanh((agg+b)/deg); znext = h @ Wn (32x32).
// 32 nodes/block, node = 8 lanes.  All node vectors bf16.
__global__ __launch_bounds__(256) void k_layer(const float* __restrict__ degs,
                                               const int* __restrict__ ell,
                                               const bf16* __restrict__ zin,
                                               const float* __restrict__ bias,
                                               const float* __restrict__ Wn,
                                               bf16* __restrict__ hout,
                                               bf16* __restrict__ znext) {
    __shared__ float wt[32 * 36];    // W transposed: wt[c][k]
    __shared__ float hl[32 * 36];
    int tid = threadIdx.x;
    for (int i = tid; i < 1024; i += 256) {
        int k = i >> 5, c = i & 31;
        wt[c * 36 + k] = Wn[i];
    }
    int blk = xcd_swz(blockIdx.x, 256);             // 2048 blocks -> chunk 256
    int r = tid >> 3, q4 = (tid & 7) * 4;
    int d = blk * 32 + r;
    float degv = degs[d];
    int cnt = (int)degv - 1;
    const int* row = ell + (size_t)d * MAXD;
    ushort4 sv = *(const ushort4*)&zin[(size_t)d * 32 + q4];   // self term
    float4 acc = {bf2f(sv.x), bf2f(sv.y), bf2f(sv.z), bf2f(sv.w)};
    acc = gatherbf(row, cnt, zin, q4, acc);
    float4 b4 = *(const float4*)&bias[q4];
    float rdeg = __builtin_amdgcn_rcpf(degv);
    float4 val;
    val.x = ftanh((acc.x + b4.x) * rdeg);
    val.y = ftanh((acc.y + b4.y) * rdeg);
    val.z = ftanh((acc.z + b4.z) * rdeg);
    val.w = ftanh((acc.w + b4.w) * rdeg);
    ushort4 hv4 = {f2bf(val.x), f2bf(val.y), f2bf(val.z), f2bf(val.w)};
    *(ushort4*)&hout[(size_t)d * 32 + q4] = hv4;
    *(float4*)&hl[r * 36 + q4] = val;
    __syncthreads();
    #pragma unroll
    for (int it = 0; it < 4; ++it) {
        int wid = tid + it * 256;
        int n = wid >> 5, c = wid & 31;
        const float* hrow = &hl[n * 36];
        const float* wrow = &wt[c * 36];
        float4 a4 = {0.f, 0.f, 0.f, 0.f};
        #pragma unroll
        for (int k = 0; k < 32; k += 4) {
            float4 hv = *(const float4*)&hrow[k];
            float4 wv = *(const float4*)&wrow[k];
            a4.x += hv.x * wv.x; a4.y += hv.y * wv.y;
            a4.z += hv.z * wv.z; a4.w += hv.w * wv.w;
        }
        znext[(size_t)(blk * 32 + n) * 32 + c] =
            f2bf((a4.x + a4.y) + (a4.z + a4.w));
    }
}

// ---------------------------------------------------------------------------
// Layer-3 variant: z4 = h3 @ W3 is 1-wide (f32) -> in-group reduce.
__global__ __launch_bounds__(256) void k_layer3(const float* __restrict__ degs,
                                                const int* __restrict__ ell,
                                                const bf16* __restrict__ zin,
                                                const float* __restrict__ bias,
                                                const float* __restrict__ W3,
                                                bf16* __restrict__ hout,
                                                float* __restrict__ z4) {
    int tid = threadIdx.x;
    int blk = xcd_swz(blockIdx.x, 256);
    int r = tid >> 3, q4 = (tid & 7) * 4;
    int d = blk * 32 + r;
    float degv = degs[d];
    int cnt = (int)degv - 1;
    const int* row = ell + (size_t)d * MAXD;
    ushort4 sv = *(const ushort4*)&zin[(size_t)d * 32 + q4];
    float4 acc = {bf2f(sv.x), bf2f(sv.y), bf2f(sv.z), bf2f(sv.w)};
    acc = gatherbf(row, cnt, zin, q4, acc);
    float4 b4 = *(const float4*)&bias[q4];
    float rdeg = __builtin_amdgcn_rcpf(degv);
    float4 val;
    val.x = ftanh((acc.x + b4.x) * rdeg);
    val.y = ftanh((acc.y + b4.y) * rdeg);
    val.z = ftanh((acc.z + b4.z) * rdeg);
    val.w = ftanh((acc.w + b4.w) * rdeg);
    ushort4 hv4 = {f2bf(val.x), f2bf(val.y), f2bf(val.z), f2bf(val.w)};
    *(ushort4*)&hout[(size_t)d * 32 + q4] = hv4;
    float4 w4 = *(const float4*)&W3[q4];
    float v = (val.x * w4.x + val.y * w4.y) + (val.z * w4.z + val.w * w4.w);
    v += __shfl_xor(v, 1, 8);
    v += __shfl_xor(v, 2, 8);
    v += __shfl_xor(v, 4, 8);
    if ((tid & 7) == 0) z4[d] = v;
}

// ---------------------------------------------------------------------------
// Fused: layer-4 gather (1-wide f32) -> h4; msg=[h1 h2 h3 h4] (bf16 reads);
// phi=relu(msg@phiW+b); per-graph partial sum -> one atomicAdd set per block.
__global__ __launch_bounds__(512) void k_phi(const float* __restrict__ degs,
                                             const int* __restrict__ ell,
                                             const float* __restrict__ z4,
                                             const float* __restrict__ b3,
                                             const bf16* __restrict__ h1,
                                             const bf16* __restrict__ h2,
                                             const bf16* __restrict__ h3,
                                             const float* __restrict__ phiW,
                                             const float* __restrict__ phib,
                                             float* __restrict__ summed) {
    __shared__ float pl[30 * 100];   // phiW transposed: pl[c][j]
    __shared__ float ml[16 * 100];   // msg rows (f32 in LDS)
    __shared__ float part[8][32];
    int tid = threadIdx.x;
    for (int i = tid; i < 30 * 97; i += 512) {
        int cc = i / 97, jj = i - cc * 97;
        pl[cc * 100 + jj] = phiW[jj * 30 + cc];
    }
    int blk = xcd_swz(blockIdx.x, 512);             // 4096 blocks -> chunk 512
    int r = tid >> 5, c = tid & 31;
    int d = blk * 16 + r;
    int g = d >> 11;
    float degv = degs[d];
    int cnt = (int)degv - 1; if (cnt > MAXD) cnt = MAXD;
    const int* row = ell + (size_t)d * MAXD;
    float acc = 0.f;
    for (int j = c; j < cnt; j += 32) acc += z4[row[j]];
    #pragma unroll
    for (int off = 16; off; off >>= 1) acc += __shfl_xor(acc, off, 32);
    float h4 = ftanh((acc + z4[d] + b3[0]) * __builtin_amdgcn_rcpf(degv));
    ml[r * 100 + c]      = bf2f(h1[(size_t)d * 32 + c]);
    ml[r * 100 + 32 + c] = bf2f(h2[(size_t)d * 32 + c]);
    ml[r * 100 + 64 + c] = bf2f(h3[(size_t)d * 32 + c]);
    if (c == 0) ml[r * 100 + 96] = h4;
    __syncthreads();
    float s = 0.f;
    if (c < 30) {
        const float* mrow = ml + r * 100;
        const float* prow = pl + c * 100;
        float4 a4 = {0.f, 0.f, 0.f, 0.f};
        #pragma unroll
        for (int j = 0; j < 96; j += 4) {
            float4 mv = *(const float4*)&mrow[j];
            float4 pv = *(const float4*)&prow[j];
            a4.x += mv.x * pv.x; a4.y += mv.y * pv.y;
            a4.z += mv.z * pv.z; a4.w += mv.w * pv.w;
        }
        s = (a4.x + a4.y) + (a4.z + a4.w) + mrow[96] * prow[96] + phib[c];
        s = fmaxf(s, 0.f);
    }
    s += __shfl_down(s, 32);                 // node pair within each wave
    int wave = tid >> 6;
    if ((tid & 63) < 32) part[wave][tid & 31] = s;
    __syncthreads();
    if (tid < 32) {
        float tot = 0.f;
        #pragma unroll
        for (int w = 0; w < 8; ++w) tot += part[w][tid];
        if (tid < 30) atomicAdd(&summed[g * 30 + tid], tot);
    }
}

// ---------------------------------------------------------------------------
// out = summed @ rhoW + rhob   (32x30 @ 30x32)
__global__ __launch_bounds__(1024) void k_rho(const float* __restrict__ summed,
                                              const float* __restrict__ rhoW,
                                              const float* __restrict__ rhob,
                                              float* __restrict__ out) {
    int tid = threadIdx.x;
    int b = tid >> 5, o = tid & 31;
    float s = rhob[o];
    #pragma unroll
    for (int k = 0; k < 30; ++k) s += summed[b * 30 + k] * rhoW[k * 32 + o];
    out[tid] = s;
}

// ---------------------------------------------------------------------------
extern "C" void kernel_launch(void* const* d_in, const int* in_sizes, int n_in,
                              void* d_out, int out_size, void* d_ws, size_t ws_size,
                              hipStream_t stream) {
    const float* feat = (const float*)d_in[0];
    const float* degs = (const float*)d_in[1];
    const int*   ei   = (const int*)d_in[2];
    const float* W0   = (const float*)d_in[3];
    const float* b0   = (const float*)d_in[4];
    const float* W1   = (const float*)d_in[5];
    const float* b1   = (const float*)d_in[6];
    const float* W2   = (const float*)d_in[7];
    const float* b2   = (const float*)d_in[8];
    const float* W3   = (const float*)d_in[9];
    const float* b3   = (const float*)d_in[10];
    const float* phiW = (const float*)d_in[11];
    const float* phib = (const float*)d_in[12];
    const float* rhoW = (const float*)d_in[13];
    const float* rhob = (const float*)d_in[14];

    char* ws = (char*)d_ws;
    int*   cursor = (int*)(ws + WS_CURSOR);
    float* summed = (float*)(ws + WS_SUMMED);
    int*   ell    = (int*)(ws + WS_ELL);
    bf16*  za     = (bf16*)(ws + WS_ZA);
    bf16*  zb     = (bf16*)(ws + WS_ZB);
    bf16*  h1     = (bf16*)(ws + WS_H1);
    bf16*  h2     = (bf16*)(ws + WS_H2);
    bf16*  h3     = (bf16*)(ws + WS_H3);
    float* z4     = (float*)(ws + WS_Z4);
    float* out    = (float*)d_out;

    // zero cursor + summed (ws is poisoned to 0xAA before every launch)
    hipMemsetAsync(ws, 0, WS_SUMMED + NG * 30 * 4, stream);

    k_build <<<NE / 1024, 256, 0, stream>>>(ei, cursor, ell);
    k_gemm1 <<<NN / 64, 256, 0, stream>>>(feat, W0, za);
    k_layer <<<NN / 32, 256, 0, stream>>>(degs, ell, za, b0, W1, h1, zb);
    k_layer <<<NN / 32, 256, 0, stream>>>(degs, ell, zb, b1, W2, h2, za);
    k_layer3<<<NN / 32, 256, 0, stream>>>(degs, ell, za, b2, W3, h3, z4);
    k_phi   <<<NN / 16, 512, 0, stream>>>(degs, ell, z4, b3, h1, h2, h3, phiW, phib, summed);
    k_rho   <<<1, 1024, 0, stream>>>(summed, rhoW, rhob, out);
}